// Round 7
// baseline (42.265 us; speedup 1.0000x reference)
//
#include <hip/hip_runtime.h>

#define NPTS 16384
#define KS   16                  // stored bf16 k-slots per point (32 B)
#define BT   256                 // 4 waves per block
#define BROWS 256                // rows per block: 4 waves x 2 32-row tiles
#define TSPLIT 8
#define SWEEP (NPTS / TSPLIT)    // 2048 targets per block sweep
#define CHUNK 512                // targets staged in LDS per phase (16 KB)
#define NCH   (SWEEP / CHUNK)    // 4 chunks
#define CTILE (CHUNK / 32)       // 16 32-target tiles per chunk

typedef __attribute__((ext_vector_type(8)))  short bf16x8;
typedef __attribute__((ext_vector_type(16))) float f32x16;
typedef __attribute__((ext_vector_type(8)))  unsigned short ushort8;

__device__ __forceinline__ unsigned short btrunc(float f) {
    return (unsigned short)(__float_as_uint(f) >> 16);
}
__device__ __forceinline__ float btruncf(float f) {
    return __uint_as_float(__float_as_uint(f) & 0xFFFF0000u);
}

// A-role (source rows):  [-2xh, -2xl, -2xh, -2yh, -2yl, -2yh, -2zh, -2zl, -2zh, 1, 1, 0...]
// B-role (target cols):  [ xh ,  xh ,  xl ,  yh ,  yh ,  yl ,  zh ,  zh ,  zl , qh, ql, 0...]
// A(s).B(t) = -2 s.t + |t|^2   (lo*lo cross terms dropped, ~2^-16 relative)
__global__ void chamfer_pack(const float* __restrict__ s,
                             const float* __restrict__ t,
                             unsigned short* __restrict__ Apack,
                             unsigned short* __restrict__ Bpack,
                             float* __restrict__ sq,
                             unsigned* __restrict__ outinit)
{
    int i = blockIdx.x * blockDim.x + threadIdx.x;
    if (i >= 2 * NPTS) return;
    outinit[i] = 0x7F7F7F7Fu;            // huge positive float; out_size == 2*NPTS
    int cloud = i >> 14;
    int p = i & (NPTS - 1);
    const float* base = cloud ? t : s;
    float x = base[3 * p], y = base[3 * p + 1], z = base[3 * p + 2];

    float xh = btruncf(x), yh = btruncf(y), zh = btruncf(z);
    float xl = x - xh, yl = y - yh, zl = z - zh;
    float q = x * x + y * y + z * z;
    float qh = btruncf(q), ql = q - qh;

    const unsigned short one = btrunc(1.0f);
    ushort8 A0 = { btrunc(-2.f * xh), btrunc(-2.f * xl), btrunc(-2.f * xh),
                   btrunc(-2.f * yh), btrunc(-2.f * yl), btrunc(-2.f * yh),
                   btrunc(-2.f * zh), btrunc(-2.f * zl) };
    ushort8 A1 = { btrunc(-2.f * zh), one, one, 0, 0, 0, 0, 0 };
    ushort8 B0 = { btrunc(xh), btrunc(xh), btrunc(xl),
                   btrunc(yh), btrunc(yh), btrunc(yl),
                   btrunc(zh), btrunc(zh) };
    ushort8 B1 = { btrunc(zl), btrunc(qh), btrunc(ql), 0, 0, 0, 0, 0 };

    *(ushort8*)(Apack + (size_t)i * KS)     = A0;
    *(ushort8*)(Apack + (size_t)i * KS + 8) = A1;
    *(ushort8*)(Bpack + (size_t)i * KS)     = B0;
    *(ushort8*)(Bpack + (size_t)i * KS + 8) = B1;
    sq[i] = q;
}

// grid = (NPTS/BROWS=64, TSPLIT=8, 2) = 1024 blocks = 4/CU, 4 waves/SIMD.
// B staged in LDS per 512-target chunk, double-buffered, shared by 4 waves.
// LDS frag u (= t*64 + kh*32 + c) at byte u*16 holds B bytes of (col c, khalf kh, tile t).
__global__ __launch_bounds__(BT, 4)
void chamfer_mfma(const unsigned short* __restrict__ Apack,
                  const unsigned short* __restrict__ Bpack,
                  const float* __restrict__ sq,
                  unsigned* __restrict__ out)
{
    const int dir = blockIdx.z;
    const unsigned short* A = Apack + (size_t)(dir ? NPTS : 0) * KS;
    const unsigned short* B = Bpack + (size_t)(dir ? 0 : NPTS) * KS;
    const float* s2 = sq + (dir ? NPTS : 0);
    unsigned* o = out + dir * NPTS;

    const int lane = threadIdx.x & 63;
    const int wv   = threadIdx.x >> 6;
    const int n32  = lane & 31;
    const int kh   = lane >> 5;         // k-slice half (0: k0..7, 1: k8..15)

    __shared__ __align__(16) char ldsb[2][CHUNK * 32];   // 2 x 16 KB

    const int rbase = blockIdx.x * BROWS + wv * 64;
    const bf16x8 a0 = *(const bf16x8*)(A + (size_t)(rbase + n32) * KS + kh * 8);
    const bf16x8 a1 = *(const bf16x8*)(A + (size_t)(rbase + 32 + n32) * KS + kh * 8);

    f32x16 mn0, mn1, zc;
#pragma unroll
    for (int r = 0; r < 16; ++r) { mn0[r] = 1e30f; mn1[r] = 1e30f; zc[r] = 0.0f; }

    // Staging: thread j owns frags u = r*256 + wv*64 + lane (r=0..3); per load
    // instruction t = u>>6 is wave/r-uniform, per-lane bytes = t*1024 + c*32 + kh*16.
    const char* Bs = (const char*)(B + (size_t)blockIdx.y * SWEEP * KS);
    int g0, g1, g2, g3;
    {
        int u0 = wv * 64 + lane;
        g0 = ((u0)           >> 6) * 1024 + n32 * 32 + kh * 16;
        g1 = ((u0 + 256)     >> 6) * 1024 + n32 * 32 + kh * 16;
        g2 = ((u0 + 512)     >> 6) * 1024 + n32 * 32 + kh * 16;
        g3 = ((u0 + 768)     >> 6) * 1024 + n32 * 32 + kh * 16;
    }
    const int ldsoff = (wv * 64 + lane) * 16;

    uint4 v0, v1, v2, v3;
#define LOADCH(ch) { const char* p = Bs + (size_t)(ch) * (CHUNK * 32);            \
        v0 = *(const uint4*)(p + g0); v1 = *(const uint4*)(p + g1);               \
        v2 = *(const uint4*)(p + g2); v3 = *(const uint4*)(p + g3); }
#define WRITECH(bb) { char* q = &ldsb[bb][0] + ldsoff;                            \
        *(uint4*)(q)         = v0; *(uint4*)(q + 4096)  = v1;                     \
        *(uint4*)(q + 8192)  = v2; *(uint4*)(q + 12288) = v3; }

    LOADCH(0); WRITECH(0); LOADCH(1);
    __syncthreads();

    int cur = 0;
    for (int ch = 0; ch < NCH; ++ch) {
        const char* rb = &ldsb[cur][0] + kh * 512 + n32 * 16;
#pragma unroll 4
        for (int t = 0; t < CTILE; ++t) {
            bf16x8 b = *(const bf16x8*)(rb + t * 1024);      // ds_read_b128, ~2-way banks
            f32x16 c0 = __builtin_amdgcn_mfma_f32_32x32x16_bf16(a0, b, zc, 0, 0, 0);
            f32x16 c1 = __builtin_amdgcn_mfma_f32_32x32x16_bf16(a1, b, zc, 0, 0, 0);
#pragma unroll
            for (int k = 0; k < 16; ++k) mn0[k] = fminf(mn0[k], c0[k]);
#pragma unroll
            for (int k = 0; k < 16; ++k) mn1[k] = fminf(mn1[k], c1[k]);
        }
        if (ch + 1 < NCH) {
            WRITECH(cur ^ 1);                 // next chunk's data -> other buffer
            if (ch + 2 < NCH) LOADCH(ch + 2); // refill regs for chunk after
            __syncthreads();
        }
        cur ^= 1;
    }
#undef LOADCH
#undef WRITECH

    // column reduce across the 32 lanes of each half-wave group
#pragma unroll
    for (int r = 0; r < 16; ++r) {
        float u0 = mn0[r], u1 = mn1[r];
        u0 = fminf(u0, __shfl_xor(u0, 1, 32));  u1 = fminf(u1, __shfl_xor(u1, 1, 32));
        u0 = fminf(u0, __shfl_xor(u0, 2, 32));  u1 = fminf(u1, __shfl_xor(u1, 2, 32));
        u0 = fminf(u0, __shfl_xor(u0, 4, 32));  u1 = fminf(u1, __shfl_xor(u1, 4, 32));
        u0 = fminf(u0, __shfl_xor(u0, 8, 32));  u1 = fminf(u1, __shfl_xor(u1, 8, 32));
        u0 = fminf(u0, __shfl_xor(u0, 16, 32)); u1 = fminf(u1, __shfl_xor(u1, 16, 32));
        mn0[r] = u0; mn1[r] = u1;
    }

    if (n32 == 0) {
        // C/D map (32x32, r2/r3-verified): col = lane&31, row = (r&3) + 8*(r>>2) + 4*kh
#pragma unroll
        for (int r = 0; r < 16; ++r) {
            int row0 = rbase + (r & 3) + 8 * (r >> 2) + 4 * kh;
            float d0 = fmaxf(mn0[r] + s2[row0], 0.0f);
            atomicMin(&o[row0], __float_as_uint(d0));
            int row1 = row0 + 32;
            float d1 = fmaxf(mn1[r] + s2[row1], 0.0f);
            atomicMin(&o[row1], __float_as_uint(d1));
        }
    }
}

extern "C" void kernel_launch(void* const* d_in, const int* in_sizes, int n_in,
                              void* d_out, int out_size, void* d_ws, size_t ws_size,
                              hipStream_t stream) {
    const float* s = (const float*)d_in[0];
    const float* t = (const float*)d_in[1];

    unsigned short* Apack = (unsigned short*)d_ws;                 // 1 MB
    unsigned short* Bpack = Apack + (size_t)2 * NPTS * KS;         // 1 MB
    float* sq = (float*)(Bpack + (size_t)2 * NPTS * KS);           // 128 KB

    chamfer_pack<<<(2 * NPTS + BT - 1) / BT, BT, 0, stream>>>(
        s, t, Apack, Bpack, sq, (unsigned*)d_out);

    dim3 grid(NPTS / BROWS, TSPLIT, 2);
    chamfer_mfma<<<grid, BT, 0, stream>>>(Apack, Bpack, sq, (unsigned*)d_out);
}

// Round 8
// 38.397 us; speedup vs baseline: 1.1007x; 1.1007x over previous
//
#include <hip/hip_runtime.h>

#define NPTS 16384
#define KS   16                  // stored bf16 k-slots per point (32 B)
#define BT   256                 // 4 waves per block
#define BROWS 128                // rows per block: 4 waves x 1 32-row tile
#define TSPLIT 8
#define SWEEP (NPTS / TSPLIT)    // 2048 targets per block sweep
#define NTILE (SWEEP / 32)       // 64 32-target tiles

typedef __attribute__((ext_vector_type(8)))  short bf16x8;
typedef __attribute__((ext_vector_type(16))) float f32x16;
typedef __attribute__((ext_vector_type(8)))  unsigned short ushort8;

__device__ __forceinline__ unsigned short btrunc(float f) {
    return (unsigned short)(__float_as_uint(f) >> 16);
}
__device__ __forceinline__ float btruncf(float f) {
    return __uint_as_float(__float_as_uint(f) & 0xFFFF0000u);
}

// A-role (source rows):  [-2xh, -2xl, -2xh, -2yh, -2yl, -2yh, -2zh, -2zl, -2zh, 1, 1, 0...]
// B-role (target cols):  [ xh ,  xh ,  xl ,  yh ,  yh ,  yl ,  zh ,  zh ,  zl , qh, ql, 0...]
// A(s).B(t) = -2 s.t + |t|^2   (lo*lo cross terms dropped, ~2^-16 relative)
__global__ void chamfer_pack(const float* __restrict__ s,
                             const float* __restrict__ t,
                             unsigned short* __restrict__ Apack,
                             unsigned short* __restrict__ Bpack,
                             float* __restrict__ sq,
                             unsigned* __restrict__ outinit)
{
    int i = blockIdx.x * blockDim.x + threadIdx.x;
    if (i >= 2 * NPTS) return;
    outinit[i] = 0x7F7F7F7Fu;            // huge positive float; out_size == 2*NPTS
    int cloud = i >> 14;
    int p = i & (NPTS - 1);
    const float* base = cloud ? t : s;
    float x = base[3 * p], y = base[3 * p + 1], z = base[3 * p + 2];

    float xh = btruncf(x), yh = btruncf(y), zh = btruncf(z);
    float xl = x - xh, yl = y - yh, zl = z - zh;
    float q = x * x + y * y + z * z;
    float qh = btruncf(q), ql = q - qh;

    const unsigned short one = btrunc(1.0f);
    ushort8 A0 = { btrunc(-2.f * xh), btrunc(-2.f * xl), btrunc(-2.f * xh),
                   btrunc(-2.f * yh), btrunc(-2.f * yl), btrunc(-2.f * yh),
                   btrunc(-2.f * zh), btrunc(-2.f * zl) };
    ushort8 A1 = { btrunc(-2.f * zh), one, one, 0, 0, 0, 0, 0 };
    ushort8 B0 = { btrunc(xh), btrunc(xh), btrunc(xl),
                   btrunc(yh), btrunc(yh), btrunc(yl),
                   btrunc(zh), btrunc(zh) };
    ushort8 B1 = { btrunc(zl), btrunc(qh), btrunc(ql), 0, 0, 0, 0, 0 };

    *(ushort8*)(Apack + (size_t)i * KS)     = A0;
    *(ushort8*)(Apack + (size_t)i * KS + 8) = A1;
    *(ushort8*)(Bpack + (size_t)i * KS)     = B0;
    *(ushort8*)(Bpack + (size_t)i * KS + 8) = B1;
    sq[i] = q;
}

// grid = (NPTS/BROWS=128, TSPLIT=8, 2) = 2048 blocks = 8 blocks/CU = 8 waves/SIMD.
// One 32-row tile per wave; minimal live state (~55 VGPR) under the 64-reg cap.
__global__ __launch_bounds__(BT, 8)
void chamfer_mfma(const unsigned short* __restrict__ Apack,
                  const unsigned short* __restrict__ Bpack,
                  const float* __restrict__ sq,
                  unsigned* __restrict__ out)
{
    const int dir = blockIdx.z;
    const unsigned short* A = Apack + (size_t)(dir ? NPTS : 0) * KS;
    const unsigned short* B = Bpack + (size_t)(dir ? 0 : NPTS) * KS;
    const float* s2 = sq + (dir ? NPTS : 0);
    unsigned* o = out + dir * NPTS;

    const int lane = threadIdx.x & 63;
    const int wv   = threadIdx.x >> 6;
    const int n32  = lane & 31;
    const int kh   = lane >> 5;         // k-slice half (0: k0..7, 1: k8..15)

    const int rbase = blockIdx.x * BROWS + wv * 32;
    const bf16x8 a0 = *(const bf16x8*)(A + (size_t)(rbase + n32) * KS + kh * 8);

    f32x16 mn, zc;
#pragma unroll
    for (int r = 0; r < 16; ++r) { mn[r] = 1e30f; zc[r] = 0.0f; }

    const unsigned short* Bl = B + (size_t)(blockIdx.y * SWEEP + n32) * KS + kh * 8;

    for (int t = 0; t < NTILE; ++t) {
        bf16x8 b = *(const bf16x8*)(Bl + (size_t)t * 32 * KS);
        f32x16 c = __builtin_amdgcn_mfma_f32_32x32x16_bf16(a0, b, zc, 0, 0, 0);
#pragma unroll
        for (int k = 0; k < 16; ++k) mn[k] = fminf(mn[k], c[k]);
    }

    // column reduce across the 32 lanes of each half-wave group
#pragma unroll
    for (int r = 0; r < 16; ++r) {
        float v0 = mn[r];
        v0 = fminf(v0, __shfl_xor(v0, 1, 32));
        v0 = fminf(v0, __shfl_xor(v0, 2, 32));
        v0 = fminf(v0, __shfl_xor(v0, 4, 32));
        v0 = fminf(v0, __shfl_xor(v0, 8, 32));
        v0 = fminf(v0, __shfl_xor(v0, 16, 32));
        mn[r] = v0;
    }

    if (n32 == 0) {
        // C/D map (32x32, r2/r3-verified): col = lane&31, row = (r&3) + 8*(r>>2) + 4*kh
#pragma unroll
        for (int r = 0; r < 16; ++r) {
            int row = rbase + (r & 3) + 8 * (r >> 2) + 4 * kh;
            float d = fmaxf(mn[r] + s2[row], 0.0f);
            atomicMin(&o[row], __float_as_uint(d));
        }
    }
}

extern "C" void kernel_launch(void* const* d_in, const int* in_sizes, int n_in,
                              void* d_out, int out_size, void* d_ws, size_t ws_size,
                              hipStream_t stream) {
    const float* s = (const float*)d_in[0];
    const float* t = (const float*)d_in[1];

    unsigned short* Apack = (unsigned short*)d_ws;                 // 1 MB
    unsigned short* Bpack = Apack + (size_t)2 * NPTS * KS;         // 1 MB
    float* sq = (float*)(Bpack + (size_t)2 * NPTS * KS);           // 128 KB

    chamfer_pack<<<(2 * NPTS + BT - 1) / BT, BT, 0, stream>>>(
        s, t, Apack, Bpack, sq, (unsigned*)d_out);

    dim3 grid(NPTS / BROWS, TSPLIT, 2);
    chamfer_mfma<<<grid, BT, 0, stream>>>(Apack, Bpack, sq, (unsigned*)d_out);
}

// Round 9
// 36.883 us; speedup vs baseline: 1.1459x; 1.0410x over previous
//
#include <hip/hip_runtime.h>

#define NPTS 16384
#define KS   16                  // stored bf16 k-slots per point (32 B)
#define BT   256                 // 4 waves per block
#define BROWS 128                // rows per block: 4 waves x 1 32-row tile
#define TSPLIT 4
#define SWEEP (NPTS / TSPLIT)    // 4096 targets per block sweep
#define NTILE (SWEEP / 32)       // 128 32-target tiles
#define NR (NTILE / 2)           // 64 rounds of 2 tiles

typedef __attribute__((ext_vector_type(8)))  short bf16x8;
typedef __attribute__((ext_vector_type(16))) float f32x16;
typedef __attribute__((ext_vector_type(8)))  unsigned short ushort8;

__device__ __forceinline__ unsigned short btrunc(float f) {
    return (unsigned short)(__float_as_uint(f) >> 16);
}
__device__ __forceinline__ float btruncf(float f) {
    return __uint_as_float(__float_as_uint(f) & 0xFFFF0000u);
}

// A-role (source rows):  [-2xh, -2xl, -2xh, -2yh, -2yl, -2yh, -2zh, -2zl, -2zh, 1, 1, 0...]
// B-role (target cols):  [ xh ,  xh ,  xl ,  yh ,  yh ,  yl ,  zh ,  zh ,  zl , qh, ql, 0...]
// A(s).B(t) = -2 s.t + |t|^2   (lo*lo cross terms dropped, ~2^-16 relative)
__global__ void chamfer_pack(const float* __restrict__ s,
                             const float* __restrict__ t,
                             unsigned short* __restrict__ Apack,
                             unsigned short* __restrict__ Bpack,
                             float* __restrict__ sq,
                             unsigned* __restrict__ outinit)
{
    int i = blockIdx.x * blockDim.x + threadIdx.x;
    if (i >= 2 * NPTS) return;
    outinit[i] = 0x7F7F7F7Fu;            // huge positive float; out_size == 2*NPTS
    int cloud = i >> 14;
    int p = i & (NPTS - 1);
    const float* base = cloud ? t : s;
    float x = base[3 * p], y = base[3 * p + 1], z = base[3 * p + 2];

    float xh = btruncf(x), yh = btruncf(y), zh = btruncf(z);
    float xl = x - xh, yl = y - yh, zl = z - zh;
    float q = x * x + y * y + z * z;
    float qh = btruncf(q), ql = q - qh;

    const unsigned short one = btrunc(1.0f);
    ushort8 A0 = { btrunc(-2.f * xh), btrunc(-2.f * xl), btrunc(-2.f * xh),
                   btrunc(-2.f * yh), btrunc(-2.f * yl), btrunc(-2.f * yh),
                   btrunc(-2.f * zh), btrunc(-2.f * zl) };
    ushort8 A1 = { btrunc(-2.f * zh), one, one, 0, 0, 0, 0, 0 };
    ushort8 B0 = { btrunc(xh), btrunc(xh), btrunc(xl),
                   btrunc(yh), btrunc(yh), btrunc(yl),
                   btrunc(zh), btrunc(zh) };
    ushort8 B1 = { btrunc(zl), btrunc(qh), btrunc(ql), 0, 0, 0, 0, 0 };

    *(ushort8*)(Apack + (size_t)i * KS)     = A0;
    *(ushort8*)(Apack + (size_t)i * KS + 8) = A1;
    *(ushort8*)(Bpack + (size_t)i * KS)     = B0;
    *(ushort8*)(Bpack + (size_t)i * KS + 8) = B1;
    sq[i] = q;
}

// grid = (128, TSPLIT=4, 2) = 1024 blocks = 4 blocks/CU = 4 waves/SIMD.
// Per round: 2 B-tiles x 1 row-tile = 2 MFMA + 16 v_min3; depth-1 rotating prefetch.
// zc is made opaque so the compiler pins it in VGPRs instead of rematerializing
// the zero C-block before every MFMA (r3 counter evidence: ~8M excess v_mov).
__global__ __launch_bounds__(BT, 4)
void chamfer_mfma(const unsigned short* __restrict__ Apack,
                  const unsigned short* __restrict__ Bpack,
                  const float* __restrict__ sq,
                  unsigned* __restrict__ out)
{
    const int dir = blockIdx.z;
    const unsigned short* A = Apack + (size_t)(dir ? NPTS : 0) * KS;
    const unsigned short* B = Bpack + (size_t)(dir ? 0 : NPTS) * KS;
    const float* s2 = sq + (dir ? NPTS : 0);
    unsigned* o = out + dir * NPTS;

    const int lane = threadIdx.x & 63;
    const int wv   = threadIdx.x >> 6;
    const int n32  = lane & 31;
    const int kh   = lane >> 5;         // k-slice half (0: k0..7, 1: k8..15)

    const int rbase = blockIdx.x * BROWS + wv * 32;
    const bf16x8 a0 = *(const bf16x8*)(A + (size_t)(rbase + n32) * KS + kh * 8);

    f32x16 mn, zc;
#pragma unroll
    for (int r = 0; r < 16; ++r) { mn[r] = 1e30f; zc[r] = 0.0f; }
    asm volatile("" : "+v"(zc));        // opaque: no remat, stays in 16 VGPRs

    const unsigned short* Bl = B + (size_t)(blockIdx.y * SWEEP + n32) * KS + kh * 8;
#define BTILE(t) (*(const bf16x8*)(Bl + (size_t)(t) * 32 * KS))

    bf16x8 b0 = BTILE(0), b1 = BTILE(1);
    for (int r = 0; r < NR; ++r) {
        int tp = (2 * r + 2 < NTILE) ? 2 * r + 2 : 0;    // clamped prefetch idx
        bf16x8 p0 = BTILE(tp);
        bf16x8 p1 = BTILE(tp + 1);

        f32x16 c0 = __builtin_amdgcn_mfma_f32_32x32x16_bf16(a0, b0, zc, 0, 0, 0);
        f32x16 c1 = __builtin_amdgcn_mfma_f32_32x32x16_bf16(a0, b1, zc, 0, 0, 0);
#pragma unroll
        for (int k = 0; k < 16; ++k)
            mn[k] = fminf(fminf(mn[k], c0[k]), c1[k]);   // -> v_min3_f32

        b0 = p0; b1 = p1;
    }
#undef BTILE

    // column reduce across the 32 lanes of each half-wave group
#pragma unroll
    for (int r = 0; r < 16; ++r) {
        float v0 = mn[r];
        v0 = fminf(v0, __shfl_xor(v0, 1, 32));
        v0 = fminf(v0, __shfl_xor(v0, 2, 32));
        v0 = fminf(v0, __shfl_xor(v0, 4, 32));
        v0 = fminf(v0, __shfl_xor(v0, 8, 32));
        v0 = fminf(v0, __shfl_xor(v0, 16, 32));
        mn[r] = v0;
    }

    if (n32 == 0) {
        // C/D map (32x32, r2/r3-verified): col = lane&31, row = (r&3) + 8*(r>>2) + 4*kh
#pragma unroll
        for (int r = 0; r < 16; ++r) {
            int row = rbase + (r & 3) + 8 * (r >> 2) + 4 * kh;
            float d = fmaxf(mn[r] + s2[row], 0.0f);
            atomicMin(&o[row], __float_as_uint(d));
        }
    }
}

extern "C" void kernel_launch(void* const* d_in, const int* in_sizes, int n_in,
                              void* d_out, int out_size, void* d_ws, size_t ws_size,
                              hipStream_t stream) {
    const float* s = (const float*)d_in[0];
    const float* t = (const float*)d_in[1];

    unsigned short* Apack = (unsigned short*)d_ws;                 // 1 MB
    unsigned short* Bpack = Apack + (size_t)2 * NPTS * KS;         // 1 MB
    float* sq = (float*)(Bpack + (size_t)2 * NPTS * KS);           // 128 KB

    chamfer_pack<<<(2 * NPTS + BT - 1) / BT, BT, 0, stream>>>(
        s, t, Apack, Bpack, sq, (unsigned*)d_out);

    dim3 grid(NPTS / BROWS, TSPLIT, 2);
    chamfer_mfma<<<grid, BT, 0, stream>>>(Apack, Bpack, sq, (unsigned*)d_out);
}